// Round 4
// baseline (203.985 us; speedup 1.0000x reference)
//
#include <hip/hip_runtime.h>
#include <math.h>

// LocalGatedKL on MI355X (all fp32).
//  k_gemm_t     : t32 = Wt @ ft at 32x32 (1x1 conv commuted before bilinear resize).
//                 K-split 4 (grid-y x in-block half), 2 deterministic partials, pixel-major out.
//  k_resize_norm: bilinear 32->64 (half-pixel+clamp), sum 2 partials, channel-normalize -> tn,
//                 channel-mean -> tm. Block 0 seeds mnmx/acc.
//  k_sobel      : 3x3 sobel on tm (zero pad), per-image min/max via uint atomics (m >= 0)
//  k_gemm_s     : sn = normalize(Ws @ fs3); 2 px/thread, K-split 2 in-block, scalar weights
//  k_aff<0>     : 24-neighbor affinities of sn (reflect pad), log_softmax -> slogp
//  k_aff<1>     : same for tn + entropy/edge gating + KL + masked weighted reduce (double atomics)
//  k_final      : out = sum(w*kl) / (sum(w)+1e-6)
// Weights are read directly (no transpose kernel) via wave-uniform scalar loads.

#define WS_T32   0u           // 2 partials * 524288
#define WS_TN    1048576u
#define WS_SN    3145728u
#define WS_TM    5242880u
#define WS_MAG   5275648u
#define WS_MNMX  5308416u
#define WS_ACC   5308432u     // byte 21233728, 8B aligned
#define WS_SLOGP 0u           // 786432 floats, reuses t32 region (dead after resize)

static __device__ __forceinline__ int reflect_idx(int i, int n) {
  if (i < 0) i = -i;
  if (i >= n) i = 2 * n - 2 - i;
  return i;
}

// t32[part][b*1024+pix][o] partial sums. grid (128, 2) x 512 thr.
// Block: 64 px, 64 outs, 256 ch (ky); waves: q=w>>2 in-block K-half, o=w&3 out-slice.
__global__ __launch_bounds__(512, 2) void k_gemm_t(const float* __restrict__ ft,
                                                   const float* __restrict__ Wt,
                                                   float* __restrict__ t32p) {
  __shared__ __align__(16) float red[4 * 64 * 20];   // 20 KB
  const int tid = threadIdx.x;
  const int w = tid >> 6, ln = tid & 63;
  const int o = w & 3;
  const int wq = __builtin_amdgcn_readfirstlane(w >> 2);
  const int obase = __builtin_amdgcn_readfirstlane(o * 16);
  const int P0 = blockIdx.x * 64;
  const int b = P0 >> 10;
  const int pixl = (P0 & 1023) + ln;
  const int ky = blockIdx.y;
  float ac[16];
#pragma unroll
  for (int i = 0; i < 16; i++) ac[i] = 0.f;
  const float* fb = ft + (size_t)b * 524288 + (size_t)(ky * 256 + wq * 128) * 1024 + pixl;
  const float* wb = Wt + obase * 512 + ky * 256 + wq * 128;
  float n0 = fb[0], n1 = fb[1024], n2 = fb[2048], n3 = fb[3072];
  for (int c = 0; c < 128; c += 4) {
    float v0 = n0, v1 = n1, v2 = n2, v3 = n3;
    if (c + 4 < 128) {
      const float* nf = fb + (size_t)(c + 4) * 1024;
      n0 = nf[0]; n1 = nf[1024]; n2 = nf[2048]; n3 = nf[3072];
    }
#pragma unroll
    for (int oo = 0; oo < 16; oo++) {
      const float* wr = wb + oo * 512 + c;
      float w0 = wr[0], w1 = wr[1], w2 = wr[2], w3 = wr[3];
      ac[oo] += w0 * v0 + w1 * v1 + w2 * v2 + w3 * v3;
    }
  }
  if (w >= 4) {                                      // q==1 writes
#pragma unroll
    for (int j = 0; j < 4; j++)
      *(float4*)&red[(o * 64 + ln) * 20 + ((j * 4) ^ ((ln & 3) << 2))] =
          make_float4(ac[4 * j], ac[4 * j + 1], ac[4 * j + 2], ac[4 * j + 3]);
  }
  __syncthreads();
  if (w < 4) {                                       // q==0 combines + stores
#pragma unroll
    for (int j = 0; j < 4; j++) {
      float4 r = *(const float4*)&red[(o * 64 + ln) * 20 + ((j * 4) ^ ((ln & 3) << 2))];
      ac[4 * j] += r.x; ac[4 * j + 1] += r.y; ac[4 * j + 2] += r.z; ac[4 * j + 3] += r.w;
    }
    float* outp = t32p + (size_t)ky * 524288 + ((size_t)b * 1024 + pixl) * 64 + obase;
#pragma unroll
    for (int j = 0; j < 4; j++)
      *(float4*)(outp + 4 * j) =
          make_float4(ac[4 * j], ac[4 * j + 1], ac[4 * j + 2], ac[4 * j + 3]);
  }
}

// bilinear 32->64, sum 2 partials, normalize -> tn [pix][64], mean -> tm.
// thread = (pixel, channel half). 256 blocks x 256 thr. Block 0 seeds mnmx/acc.
__global__ __launch_bounds__(256) void k_resize_norm(const float* __restrict__ t32p,
                                                     float* __restrict__ tn,
                                                     float* __restrict__ tm,
                                                     unsigned int* __restrict__ mnmx,
                                                     double* __restrict__ accg) {
  if (blockIdx.x == 0) {
    int t = threadIdx.x;
    if (t < 8) mnmx[t] = 0x7F800000u;                // +inf (uint order == float order, m>=0)
    else if (t < 16) mnmx[t] = 0u;
    else if (t == 16) { accg[0] = 0.0; accg[1] = 0.0; }
  }
  const int g = blockIdx.x * 256 + threadIdx.x;      // 0..65535
  const int p = g >> 1, h = g & 1;
  const int b = p >> 12, pix = p & 4095;
  const int y = pix >> 6, x = pix & 63;
  float fy = 0.5f * y - 0.25f, fx = 0.5f * x - 0.25f;
  int y0f = (int)floorf(fy), x0f = (int)floorf(fx);
  float wy = fy - (float)y0f, wx = fx - (float)x0f;
  int y1 = min(y0f + 1, 31), x1 = min(x0f + 1, 31);
  int y0 = max(y0f, 0), x0 = max(x0f, 0);
  const int ip[4] = {y0 * 32 + x0, y0 * 32 + x1, y1 * 32 + x0, y1 * 32 + x1};
  const float wg[4] = {(1.f - wy) * (1.f - wx), (1.f - wy) * wx, wy * (1.f - wx), wy * wx};
  float v[32];
#pragma unroll
  for (int i = 0; i < 32; i++) v[i] = 0.f;
#pragma unroll
  for (int qd = 0; qd < 4; qd++) {
    float wq = wg[qd];
#pragma unroll
    for (int part = 0; part < 2; part++) {
      const float4* s4 = (const float4*)(t32p + (size_t)part * 524288
                                         + ((size_t)b * 1024 + ip[qd]) * 64 + h * 32);
#pragma unroll
      for (int cg = 0; cg < 8; cg++) {
        float4 f = s4[cg];
        v[4 * cg + 0] += wq * f.x; v[4 * cg + 1] += wq * f.y;
        v[4 * cg + 2] += wq * f.z; v[4 * cg + 3] += wq * f.w;
      }
    }
  }
  float sum = 0.f, ssq = 0.f;
#pragma unroll
  for (int i = 0; i < 32; i++) { sum += v[i]; ssq += v[i] * v[i]; }
  float sumf = sum + __shfl_xor(sum, 1);
  float ssqf = ssq + __shfl_xor(ssq, 1);
  float rn = 1.f / fmaxf(sqrtf(ssqf), 1e-12f);
  float4* tnp = (float4*)(tn + ((size_t)b * 4096 + pix) * 64 + h * 32);
#pragma unroll
  for (int cg = 0; cg < 8; cg++)
    tnp[cg] = make_float4(v[4 * cg] * rn, v[4 * cg + 1] * rn,
                          v[4 * cg + 2] * rn, v[4 * cg + 3] * rn);
  if (h == 0) tm[p] = sumf * (1.f / 64.f);
}

__global__ __launch_bounds__(128) void k_sobel(const float* __restrict__ tm,
                                               float* __restrict__ mag,
                                               unsigned int* __restrict__ mnmx) {
  const int p = blockIdx.x * 128 + threadIdx.x;
  const int b = p >> 12, pix = p & 4095;
  const int y = pix >> 6, x = pix & 63;
  const float* img = tm + (size_t)b * 4096;
  float v[3][3];
#pragma unroll
  for (int r = -1; r <= 1; r++)
#pragma unroll
    for (int c = -1; c <= 1; c++) {
      int yy = y + r, xx = x + c;
      v[r + 1][c + 1] = (yy >= 0 && yy < 64 && xx >= 0 && xx < 64) ? img[yy * 64 + xx] : 0.f;
    }
  float gx = (v[0][2] - v[0][0]) + 2.f * (v[1][2] - v[1][0]) + (v[2][2] - v[2][0]);
  float gy = (v[2][0] - v[0][0]) + 2.f * (v[2][1] - v[0][1]) + (v[2][2] - v[0][2]);
  float m = sqrtf(gx * gx + gy * gy);
  mag[p] = m;
  unsigned int mu = __float_as_uint(m);
  unsigned int mnu = mu, mxu = mu;
#pragma unroll
  for (int off = 32; off >= 1; off >>= 1) {
    mnu = min(mnu, __shfl_xor(mnu, off));
    mxu = max(mxu, __shfl_xor(mxu, off));
  }
  if ((threadIdx.x & 63) == 0) {
    atomicMin(&mnmx[b], mnu);
    atomicMax(&mnmx[8 + b], mxu);
  }
}

// sn = normalize(Ws @ fs3), pixel-major. 256 blocks x 512 thr.
// Block: 128 px (2/lane), 64 outs, K-split 2; waves: q=w>>2 K-half, o=w&3 out-slice.
__global__ __launch_bounds__(512, 2) void k_gemm_s(const float* __restrict__ fs3,
                                                   const float* __restrict__ Ws,
                                                   float* __restrict__ sn) {
  __shared__ __align__(16) float red[4 * 64 * 36];   // 36 KB
  __shared__ float ssq_l[4][132];
  const int tid = threadIdx.x;
  const int w = tid >> 6, ln = tid & 63;
  const int o = w & 3;
  const int wq = __builtin_amdgcn_readfirstlane(w >> 2);
  const int obase = __builtin_amdgcn_readfirstlane(o * 16);
  const int P0 = blockIdx.x * 128;
  const int b = P0 >> 12;
  const int pix0 = (P0 & 4095) + 2 * ln;
  float ac[2][16];
#pragma unroll
  for (int i = 0; i < 16; i++) { ac[0][i] = 0.f; ac[1][i] = 0.f; }
  const float* fb = fs3 + (size_t)b * 1048576 + (size_t)(wq * 128) * 4096 + pix0;
  const float* wb = Ws + obase * 256 + wq * 128;
  float2 n0 = *(const float2*)(fb);
  float2 n1 = *(const float2*)(fb + 4096);
  float2 n2 = *(const float2*)(fb + 8192);
  float2 n3 = *(const float2*)(fb + 12288);
  for (int c = 0; c < 128; c += 4) {
    float2 v0 = n0, v1 = n1, v2 = n2, v3 = n3;
    if (c + 4 < 128) {
      const float* nf = fb + (size_t)(c + 4) * 4096;
      n0 = *(const float2*)(nf);
      n1 = *(const float2*)(nf + 4096);
      n2 = *(const float2*)(nf + 8192);
      n3 = *(const float2*)(nf + 12288);
    }
#pragma unroll
    for (int oo = 0; oo < 16; oo++) {
      const float* wr = wb + oo * 256 + c;
      float w0 = wr[0], w1 = wr[1], w2 = wr[2], w3 = wr[3];
      ac[0][oo] += w0 * v0.x + w1 * v1.x + w2 * v2.x + w3 * v3.x;
      ac[1][oo] += w0 * v0.y + w1 * v1.y + w2 * v2.y + w3 * v3.y;
    }
  }
  if (w >= 4) {
#pragma unroll
    for (int p2 = 0; p2 < 2; p2++)
#pragma unroll
      for (int j = 0; j < 4; j++)
        *(float4*)&red[(o * 64 + ln) * 36 + (((p2 * 16 + j * 4)) ^ ((ln & 7) << 2))] =
            make_float4(ac[p2][4 * j], ac[p2][4 * j + 1], ac[p2][4 * j + 2], ac[p2][4 * j + 3]);
  }
  __syncthreads();
  float ss0 = 0.f, ss1 = 0.f;
  if (w < 4) {
#pragma unroll
    for (int p2 = 0; p2 < 2; p2++)
#pragma unroll
      for (int j = 0; j < 4; j++) {
        float4 r = *(const float4*)&red[(o * 64 + ln) * 36 + (((p2 * 16 + j * 4)) ^ ((ln & 7) << 2))];
        ac[p2][4 * j] += r.x; ac[p2][4 * j + 1] += r.y;
        ac[p2][4 * j + 2] += r.z; ac[p2][4 * j + 3] += r.w;
      }
#pragma unroll
    for (int i = 0; i < 16; i++) { ss0 += ac[0][i] * ac[0][i]; ss1 += ac[1][i] * ac[1][i]; }
    ssq_l[o][2 * ln] = ss0;
    ssq_l[o][2 * ln + 1] = ss1;
  }
  __syncthreads();
  if (w < 4) {
    float t0 = ssq_l[0][2 * ln] + ssq_l[1][2 * ln] + ssq_l[2][2 * ln] + ssq_l[3][2 * ln];
    float t1 = ssq_l[0][2 * ln + 1] + ssq_l[1][2 * ln + 1] + ssq_l[2][2 * ln + 1] + ssq_l[3][2 * ln + 1];
    float rn0 = 1.f / fmaxf(sqrtf(t0), 1e-12f);
    float rn1 = 1.f / fmaxf(sqrtf(t1), 1e-12f);
    float* ob = sn + ((size_t)b * 4096 + pix0) * 64 + obase;
#pragma unroll
    for (int j = 0; j < 4; j++) {
      *(float4*)(ob + 4 * j) = make_float4(ac[0][4 * j] * rn0, ac[0][4 * j + 1] * rn0,
                                           ac[0][4 * j + 2] * rn0, ac[0][4 * j + 3] * rn0);
      *(float4*)(ob + 64 + 4 * j) = make_float4(ac[1][4 * j] * rn1, ac[1][4 * j + 1] * rn1,
                                                ac[1][4 * j + 2] * rn1, ac[1][4 * j + 3] * rn1);
    }
  }
}

// 24-neighbor affinity + log_softmax; 8x8 tile, 12x12 reflect halo, 64 ch staged once.
// LDS [144 pos][68] + XOR swizzle (verified conflict-free for window reads).
template <int TPASS>
__global__ __launch_bounds__(256) void k_aff(const float* __restrict__ fn,
                                             float* __restrict__ slogp,
                                             const float* __restrict__ mag,
                                             const unsigned int* __restrict__ mnmx,
                                             double* __restrict__ accg) {
  __shared__ __align__(16) float fl[144 * 68];   // 39.2 KB
  const int tid = threadIdx.x;
  const int wvu = __builtin_amdgcn_readfirstlane(tid >> 6);
  const int ln = tid & 63;
  const int b = blockIdx.x >> 6, tl = blockIdx.x & 63;
  const int ty0 = (tl >> 3) * 8, tx0 = (tl & 7) * 8;
  const int ty = ln >> 3, tx = ln & 7;
#pragma unroll
  for (int i = 0; i < 9; i++) {                  // 2304 float4 / 256 thr
    int flat = i * 256 + tid;
    int pos = flat >> 4, cg = flat & 15;
    int hy = pos / 12, hx = pos - hy * 12;
    int gy2 = reflect_idx(ty0 + hy - 2, 64);
    int gx2 = reflect_idx(tx0 + hx - 2, 64);
    float4 f = *(const float4*)(fn + ((size_t)b * 4096 + gy2 * 64 + gx2) * 64 + cg * 4);
    int sw = (((pos * 17) >> 3) & 3) << 2;
    *(float4*)(&fl[pos * 68 + ((cg * 4) ^ sw)]) = f;
  }
  __syncthreads();
  const int base = ty * 12 + tx;
  const int cbase = wvu * 16;
  float4 cv[4];
  {
    int cp = base + 26;                          // center
    int cs = (((cp * 17) >> 3) & 3) << 2;
    const float* crow = &fl[cp * 68];
#pragma unroll
    for (int j = 0; j < 4; j++) cv[j] = *(const float4*)(crow + ((cbase + 4 * j) ^ cs));
  }
  float aff[24];
  {
    int n = 0;
#pragma unroll
    for (int dy = 0; dy < 5; dy++)
#pragma unroll
      for (int dx = 0; dx < 5; dx++) {
        if (dy == 2 && dx == 2) continue;
        int pp = base + dy * 12 + dx;
        int sw2 = (((pp * 17) >> 3) & 3) << 2;
        const float* rowp = &fl[pp * 68];
        float4 q0 = *(const float4*)(rowp + ((cbase + 0) ^ sw2));
        float4 q1 = *(const float4*)(rowp + ((cbase + 4) ^ sw2));
        float4 q2 = *(const float4*)(rowp + ((cbase + 8) ^ sw2));
        float4 q3 = *(const float4*)(rowp + ((cbase + 12) ^ sw2));
        aff[n] = cv[0].x * q0.x + cv[0].y * q0.y + cv[0].z * q0.z + cv[0].w * q0.w
               + cv[1].x * q1.x + cv[1].y * q1.y + cv[1].z * q1.z + cv[1].w * q1.w
               + cv[2].x * q2.x + cv[2].y * q2.y + cv[2].z * q2.z + cv[2].w * q2.w
               + cv[3].x * q3.x + cv[3].y * q3.y + cv[3].z * q3.z + cv[3].w * q3.w;
        n++;
      }
  }
  __syncthreads();
  float* r = fl;                                 // reduce buffer [256][25]
#pragma unroll
  for (int n = 0; n < 24; n++) r[(wvu * 64 + ln) * 25 + n] = aff[n];
  __syncthreads();
  if (wvu != 0) return;
  float a[24];
#pragma unroll
  for (int n = 0; n < 24; n++)
    a[n] = r[ln * 25 + n] + r[(64 + ln) * 25 + n] + r[(128 + ln) * 25 + n] + r[(192 + ln) * 25 + n];
  float mxa = a[0];
#pragma unroll
  for (int n = 1; n < 24; n++) mxa = fmaxf(mxa, a[n]);
  float e[24]; float sum = 0.f;
#pragma unroll
  for (int n = 0; n < 24; n++) { e[n] = expf((a[n] - mxa) * 10.f); sum += e[n]; }
  float lse = logf(sum);
  const int gy = ty0 + ty, gx = tx0 + tx;
  const int gpix = b * 4096 + gy * 64 + gx;
  if (TPASS == 0) {
#pragma unroll
    for (int n = 0; n < 24; n++)
      slogp[(size_t)n * 32768 + gpix] = (a[n] - mxa) * 10.f - lse;
  } else {
    float rs = 1.f / sum;
    float ent = 0.f, kl = 0.f;
#pragma unroll
    for (int n = 0; n < 24; n++) {
      float tp = e[n] * rs;
      float tlp = (a[n] - mxa) * 10.f - lse;
      ent -= tp * tlp;
      kl += tp * (tlp - slogp[(size_t)n * 32768 + gpix]);
    }
    float wconf = 1.f - ent * (1.0f / 3.17805383034794580f);   // MAXH = log(24)
    wconf = fminf(fmaxf(wconf, 0.f), 1.f);
    float mnv = __uint_as_float(mnmx[b]);
    float mxv = __uint_as_float(mnmx[8 + b]);
    float wedge = (mag[gpix] - mnv) / (mxv - mnv + 1e-6f);
    float wgt = wconf * wconf * (1.f + wedge);
    if (gy < 2 || gy >= 62 || gx < 2 || gx >= 62) wgt = 0.f;
    double wkl = (double)(wgt * kl), wsum = (double)wgt;
#pragma unroll
    for (int off = 32; off >= 1; off >>= 1) {
      wkl  += __shfl_down(wkl, off);
      wsum += __shfl_down(wsum, off);
    }
    if (ln == 0) { atomicAdd(&accg[0], wkl); atomicAdd(&accg[1], wsum); }
  }
}

__global__ void k_final(const double* __restrict__ accg, float* __restrict__ out) {
  out[0] = (float)(accg[0] / (accg[1] + 1e-6));
}

extern "C" void kernel_launch(void* const* d_in, const int* in_sizes, int n_in,
                              void* d_out, int out_size, void* d_ws, size_t ws_size,
                              hipStream_t stream) {
  const float* fs3 = (const float*)d_in[0];
  const float* ft  = (const float*)d_in[1];
  const float* Ws  = (const float*)d_in[2];
  const float* Wt  = (const float*)d_in[3];
  float* out = (float*)d_out;
  float* w = (float*)d_ws;
  float* t32   = w + WS_T32;
  float* tn    = w + WS_TN;
  float* sn    = w + WS_SN;
  float* tm    = w + WS_TM;
  float* mag   = w + WS_MAG;
  float* slogp = w + WS_SLOGP;                   // reuses t32 region
  unsigned int* mnmx = (unsigned int*)(w + WS_MNMX);
  double* acc = (double*)(w + WS_ACC);

  k_gemm_t<<<dim3(128, 2), 512, 0, stream>>>(ft, Wt, t32);
  k_resize_norm<<<256, 256, 0, stream>>>(t32, tn, tm, mnmx, acc);
  k_sobel<<<256, 128, 0, stream>>>(tm, mag, mnmx);
  k_gemm_s<<<256, 512, 0, stream>>>(fs3, Ws, sn);
  k_aff<0><<<512, 256, 0, stream>>>(sn, slogp, nullptr, nullptr, nullptr);
  k_aff<1><<<512, 256, 0, stream>>>(tn, slogp, mag, mnmx, acc);
  k_final<<<1, 1, 0, stream>>>(acc, out);
}

// Round 8
// 200.402 us; speedup vs baseline: 1.0179x; 1.0179x over previous
//
#include <hip/hip_runtime.h>
#include <math.h>

// LocalGatedKL on MI355X (all fp32).
//  k_transw     : WtT[c][64], WsT[c][64] transposes + seed mnmx/counter/acc
//  k_gemm_t     : t32 = Wt @ ft at 32x32 (conv commuted before resize), grid-y K-split 4,
//                 out-split-8 waves, dwordx8 scalar weights double-buffered, channel-major out
//  k_resize_norm: bilinear 32->64 (half-pixel+clamp), sum 4 partials, normalize -> tn [pix][64],
//                 channel-mean -> tm. Coalesced channel-major reads.
//  k_sobel      : 3x3 sobel on tm (zero pad), per-image min/max via uint atomics (m >= 0)
//  k_gemm_s     : sn = normalize(Ws @ fs3) -> [pix][64]; same GEMM structure, K=256 sequential
//  k_aff        : FUSED s+t affinities (reflect pad, log_softmax) + entropy/edge gating + KL +
//                 masked weighted reduce + last-block finalize (atomic counter). No slogp buffer.

#define WS_T32   0u
#define WS_TN    2097152u
#define WS_SN    4194304u
#define WS_TM    6291456u
#define WS_MAG   6324224u
#define WS_WTT   6356992u
#define WS_WST   6389760u
#define WS_MNMX  6406144u     // 24 uints (16 minmax + counter)
#define WS_ACC   6406168u     // 2 doubles, byte off 25624672 (8B aligned)

static __device__ __forceinline__ int reflect_idx(int i, int n) {
  if (i < 0) i = -i;
  if (i >= n) i = 2 * n - 2 - i;
  return i;
}

// Transposes + seeding.
__global__ __launch_bounds__(256) void k_transw(const float* __restrict__ Wt,
                                                const float* __restrict__ Ws,
                                                float* __restrict__ WtT,
                                                float* __restrict__ WsT,
                                                unsigned int* __restrict__ mnmx,
                                                double* __restrict__ accg) {
  if (blockIdx.x == 0) {
    int t = threadIdx.x;
    if (t < 8) mnmx[t] = 0x7F800000u;          // +inf (uint order == float order for m >= 0)
    else if (t < 16) mnmx[t] = 0u;             // 0.0f
    else if (t == 16) mnmx[16] = 0u;           // completion counter
    else if (t == 17) accg[0] = 0.0;
    else if (t == 18) accg[1] = 0.0;
  }
  int idx = blockIdx.x * 256 + threadIdx.x;    // 0..49151
  if (idx < 32768) {
    int o = idx >> 9, c = idx & 511;
    WtT[c * 64 + o] = Wt[idx];
  } else {
    int j = idx - 32768;
    int o = j >> 8, c = j & 255;
    WsT[c * 64 + o] = Ws[j];
  }
}

// Weight-group loader: 4 channels x 8 outs from WT[c][64] slice (uniform -> s_load_dwordx8).
#define LW(WB, CC, A0, A1, B0, B1, C0, C1, D0, D1)                         \
  { const float4* q0 = (const float4*)((WB) + (CC) * 64);       A0 = q0[0]; A1 = q0[1]; \
    const float4* q1 = (const float4*)((WB) + ((CC) + 1) * 64); B0 = q1[0]; B1 = q1[1]; \
    const float4* q2 = (const float4*)((WB) + ((CC) + 2) * 64); C0 = q2[0]; C1 = q2[1]; \
    const float4* q3 = (const float4*)((WB) + ((CC) + 3) * 64); D0 = q3[0]; D1 = q3[1]; }

#define FMA_GROUP(AC)                                                       \
  { AC[0] += w00.x * v0 + w10.x * v1 + w20.x * v2 + w30.x * v3;             \
    AC[1] += w00.y * v0 + w10.y * v1 + w20.y * v2 + w30.y * v3;             \
    AC[2] += w00.z * v0 + w10.z * v1 + w20.z * v2 + w30.z * v3;             \
    AC[3] += w00.w * v0 + w10.w * v1 + w20.w * v2 + w30.w * v3;             \
    AC[4] += w01.x * v0 + w11.x * v1 + w21.x * v2 + w31.x * v3;             \
    AC[5] += w01.y * v0 + w11.y * v1 + w21.y * v2 + w31.y * v3;             \
    AC[6] += w01.z * v0 + w11.z * v1 + w21.z * v2 + w31.z * v3;             \
    AC[7] += w01.w * v0 + w11.w * v1 + w21.w * v2 + w31.w * v3; }

#define ROT8() { w00 = x00; w01 = x01; w10 = x10; w11 = x11;                \
                 w20 = x20; w21 = x21; w30 = x30; w31 = x31;                \
                 v0 = u0; v1 = u1; v2 = u2; v3 = u3; }

// t32 partials, channel-major: t32p[((part*8+b)*64+o)*1024 + pix]. grid (128,4) x 512.
__global__ __launch_bounds__(512, 4) void k_gemm_t(const float* __restrict__ ft,
                                                   const float* __restrict__ WtT,
                                                   float* __restrict__ t32p) {
  const int tid = threadIdx.x;
  const int w = tid >> 6, ln = tid & 63;
  const int o0 = __builtin_amdgcn_readfirstlane(w * 8);
  const int bx = blockIdx.x;
  const int b = bx >> 4;
  const int pixl = (bx & 15) * 64 + ln;
  const int part = blockIdx.y;
  const float* fb = ft + (size_t)b * 524288 + (size_t)(part * 128) * 1024 + pixl;
  const float* wb = WtT + (part * 128) * 64 + o0;
  float ac[8];
#pragma unroll
  for (int j = 0; j < 8; j++) ac[j] = 0.f;
  float4 w00, w01, w10, w11, w20, w21, w30, w31;
  float v0, v1, v2, v3;
  LW(wb, 0, w00, w01, w10, w11, w20, w21, w30, w31);
  { const float* f = fb; v0 = f[0]; v1 = f[1024]; v2 = f[2048]; v3 = f[3072]; }
  for (int c = 0; c < 128; c += 4) {
    float4 x00 = {0,0,0,0}, x01 = x00, x10 = x00, x11 = x00, x20 = x00, x21 = x00, x30 = x00, x31 = x00;
    float u0 = 0.f, u1 = 0.f, u2 = 0.f, u3 = 0.f;
    if (c + 4 < 128) {
      LW(wb, c + 4, x00, x01, x10, x11, x20, x21, x30, x31);
      const float* f = fb + (size_t)(c + 4) * 1024;
      u0 = f[0]; u1 = f[1024]; u2 = f[2048]; u3 = f[3072];
    }
    FMA_GROUP(ac);
    ROT8();
  }
  float* ob = t32p + (((size_t)part * 8 + b) * 64 + o0) * 1024 + pixl;
#pragma unroll
  for (int j = 0; j < 8; j++) ob[(size_t)j * 1024] = ac[j];
}

// bilinear 32->64, sum 4 partials, normalize -> tn [pix][64], mean -> tm.
// thread = (pixel, 16-ch quarter). 512 blocks x 256 thr.
__global__ __launch_bounds__(256, 4) void k_resize_norm(const float* __restrict__ t32p,
                                                        float* __restrict__ tn,
                                                        float* __restrict__ tm) {
  const int g = blockIdx.x * 256 + threadIdx.x;   // 0..131071
  const int p = g >> 2, q = g & 3;
  const int b = p >> 12, pix = p & 4095;
  const int y = pix >> 6, x = pix & 63;
  float fy = 0.5f * y - 0.25f, fx = 0.5f * x - 0.25f;
  int y0f = (int)floorf(fy), x0f = (int)floorf(fx);
  float wy = fy - (float)y0f, wx = fx - (float)x0f;
  int y1 = min(y0f + 1, 31), x1 = min(x0f + 1, 31);
  int y0 = max(y0f, 0), x0 = max(x0f, 0);
  const int ip[4] = {y0 * 32 + x0, y0 * 32 + x1, y1 * 32 + x0, y1 * 32 + x1};
  const float wg[4] = {(1.f - wy) * (1.f - wx), (1.f - wy) * wx, wy * (1.f - wx), wy * wx};
  float v[16];
#pragma unroll
  for (int i = 0; i < 16; i++) v[i] = 0.f;
#pragma unroll
  for (int cr = 0; cr < 4; cr++) {
    float wq = wg[cr];
#pragma unroll
    for (int part = 0; part < 4; part++) {
      const float* base = t32p + (((size_t)part * 8 + b) * 64 + q * 16) * 1024 + ip[cr];
#pragma unroll
      for (int c = 0; c < 16; c++) v[c] += wq * base[(size_t)c * 1024];
    }
  }
  float sum = 0.f, ssq = 0.f;
#pragma unroll
  for (int i = 0; i < 16; i++) { sum += v[i]; ssq += v[i] * v[i]; }
  float s1 = sum + __shfl_xor(sum, 1);  float sumf = s1 + __shfl_xor(s1, 2);
  float q1 = ssq + __shfl_xor(ssq, 1);  float ssqf = q1 + __shfl_xor(q1, 2);
  float rn = 1.f / fmaxf(sqrtf(ssqf), 1e-12f);
  float* tp = tn + ((size_t)b * 4096 + pix) * 64 + q * 16;
#pragma unroll
  for (int j = 0; j < 4; j++)
    *(float4*)(tp + 4 * j) = make_float4(v[4 * j] * rn, v[4 * j + 1] * rn,
                                         v[4 * j + 2] * rn, v[4 * j + 3] * rn);
  if (q == 0) tm[p] = sumf * (1.f / 64.f);
}

__global__ __launch_bounds__(128) void k_sobel(const float* __restrict__ tm,
                                               float* __restrict__ mag,
                                               unsigned int* __restrict__ mnmx) {
  const int p = blockIdx.x * 128 + threadIdx.x;
  const int b = p >> 12, pix = p & 4095;
  const int y = pix >> 6, x = pix & 63;
  const float* img = tm + (size_t)b * 4096;
  float v[3][3];
#pragma unroll
  for (int r = -1; r <= 1; r++)
#pragma unroll
    for (int c = -1; c <= 1; c++) {
      int yy = y + r, xx = x + c;
      v[r + 1][c + 1] = (yy >= 0 && yy < 64 && xx >= 0 && xx < 64) ? img[yy * 64 + xx] : 0.f;
    }
  float gx = (v[0][2] - v[0][0]) + 2.f * (v[1][2] - v[1][0]) + (v[2][2] - v[2][0]);
  float gy = (v[2][0] - v[0][0]) + 2.f * (v[2][1] - v[0][1]) + (v[2][2] - v[0][2]);
  float m = sqrtf(gx * gx + gy * gy);
  mag[p] = m;
  unsigned int mu = __float_as_uint(m);
  unsigned int mnu = mu, mxu = mu;
#pragma unroll
  for (int off = 32; off >= 1; off >>= 1) {
    mnu = min(mnu, __shfl_xor(mnu, off));
    mxu = max(mxu, __shfl_xor(mxu, off));
  }
  if ((threadIdx.x & 63) == 0) {
    atomicMin(&mnmx[b], mnu);
    atomicMax(&mnmx[8 + b], mxu);
  }
}

// sn = normalize(Ws @ fs3) -> [pix][64]. grid 512 x 512 thr; K=256 sequential.
__global__ __launch_bounds__(512, 4) void k_gemm_s(const float* __restrict__ fs3,
                                                   const float* __restrict__ WsT,
                                                   float* __restrict__ sn) {
  __shared__ float ssq_l[8][64];
  const int tid = threadIdx.x;
  const int w = tid >> 6, ln = tid & 63;
  const int o0 = __builtin_amdgcn_readfirstlane(w * 8);
  const int bx = blockIdx.x;
  const int b = bx >> 6;
  const int pixl = (bx & 63) * 64 + ln;
  const float* fb = fs3 + (size_t)b * 1048576 + pixl;
  const float* wb = WsT + o0;
  float ac[8];
#pragma unroll
  for (int j = 0; j < 8; j++) ac[j] = 0.f;
  float4 w00, w01, w10, w11, w20, w21, w30, w31;
  float v0, v1, v2, v3;
  LW(wb, 0, w00, w01, w10, w11, w20, w21, w30, w31);
  { const float* f = fb; v0 = f[0]; v1 = f[4096]; v2 = f[8192]; v3 = f[12288]; }
  for (int c = 0; c < 256; c += 4) {
    float4 x00 = {0,0,0,0}, x01 = x00, x10 = x00, x11 = x00, x20 = x00, x21 = x00, x30 = x00, x31 = x00;
    float u0 = 0.f, u1 = 0.f, u2 = 0.f, u3 = 0.f;
    if (c + 4 < 256) {
      LW(wb, c + 4, x00, x01, x10, x11, x20, x21, x30, x31);
      const float* f = fb + (size_t)(c + 4) * 4096;
      u0 = f[0]; u1 = f[4096]; u2 = f[8192]; u3 = f[12288];
    }
    FMA_GROUP(ac);
    ROT8();
  }
  float ss = 0.f;
#pragma unroll
  for (int j = 0; j < 8; j++) ss += ac[j] * ac[j];
  ssq_l[w][ln] = ss;
  __syncthreads();
  float tot = 0.f;
#pragma unroll
  for (int j = 0; j < 8; j++) tot += ssq_l[j][ln];
  float rn = 1.f / fmaxf(sqrtf(tot), 1e-12f);
  float* ob = sn + ((size_t)b * 4096 + pixl) * 64 + o0;
  *(float4*)ob       = make_float4(ac[0] * rn, ac[1] * rn, ac[2] * rn, ac[3] * rn);
  *(float4*)(ob + 4) = make_float4(ac[4] * rn, ac[5] * rn, ac[6] * rn, ac[7] * rn);
}

// 24-window partial affinities over a [144][68]-swizzled LDS tile (16 ch per wave).
static __device__ __forceinline__ void windows24(const float* flb, int base, int cbase,
                                                 float* aff) {
  float4 cv[4];
  {
    int cp = base + 26;
    int cs = (((cp * 17) >> 3) & 3) << 2;
    const float* crow = flb + cp * 68;
#pragma unroll
    for (int j = 0; j < 4; j++) cv[j] = *(const float4*)(crow + ((cbase + 4 * j) ^ cs));
  }
  int n = 0;
#pragma unroll
  for (int dy = 0; dy < 5; dy++)
#pragma unroll
    for (int dx = 0; dx < 5; dx++) {
      if (dy == 2 && dx == 2) continue;
      int pp = base + dy * 12 + dx;
      int sw2 = (((pp * 17) >> 3) & 3) << 2;
      const float* rowp = flb + pp * 68;
      float4 q0 = *(const float4*)(rowp + ((cbase + 0) ^ sw2));
      float4 q1 = *(const float4*)(rowp + ((cbase + 4) ^ sw2));
      float4 q2 = *(const float4*)(rowp + ((cbase + 8) ^ sw2));
      float4 q3 = *(const float4*)(rowp + ((cbase + 12) ^ sw2));
      aff[n] = cv[0].x * q0.x + cv[0].y * q0.y + cv[0].z * q0.z + cv[0].w * q0.w
             + cv[1].x * q1.x + cv[1].y * q1.y + cv[1].z * q1.z + cv[1].w * q1.w
             + cv[2].x * q2.x + cv[2].y * q2.y + cv[2].z * q2.z + cv[2].w * q2.w
             + cv[3].x * q3.x + cv[3].y * q3.y + cv[3].z * q3.z + cv[3].w * q3.w;
      n++;
    }
}

// Fused s+t affinity + log_softmax + gating + KL + reduce + last-block finalize.
__global__ __launch_bounds__(256, 2) void k_aff(const float* __restrict__ snp,
                                                const float* __restrict__ tnp,
                                                const float* __restrict__ mag,
                                                const unsigned int* __restrict__ mnmx,
                                                unsigned int* __restrict__ cnt,
                                                double* __restrict__ accg,
                                                float* __restrict__ out) {
  __shared__ __align__(16) float fl[2 * 144 * 68];   // 78.3 KB (s tile, t tile)
  const int tid = threadIdx.x;
  const int wvu = __builtin_amdgcn_readfirstlane(tid >> 6);
  const int ln = tid & 63;
  const int b = blockIdx.x >> 6, tl = blockIdx.x & 63;
  const int ty0 = (tl >> 3) * 8, tx0 = (tl & 7) * 8;
  const int ty = ln >> 3, tx = ln & 7;
#pragma unroll
  for (int t2 = 0; t2 < 2; t2++) {
    const float* src = t2 ? tnp : snp;
    float* dst = fl + t2 * 9792;
#pragma unroll
    for (int i = 0; i < 9; i++) {                  // 2304 float4 / 256 thr
      int flat = i * 256 + tid;
      int pos = flat >> 4, cg = flat & 15;
      int hy = pos / 12, hx = pos - hy * 12;
      int gy2 = reflect_idx(ty0 + hy - 2, 64);
      int gx2 = reflect_idx(tx0 + hx - 2, 64);
      float4 f = *(const float4*)(src + ((size_t)b * 4096 + gy2 * 64 + gx2) * 64 + cg * 4);
      int sw = (((pos * 17) >> 3) & 3) << 2;
      *(float4*)(&dst[pos * 68 + ((cg * 4) ^ sw)]) = f;
    }
  }
  __syncthreads();
  const int base = ty * 12 + tx;
  const int cbase = wvu * 16;
  float affs[24], afft[24];
  windows24(fl, base, cbase, affs);
  windows24(fl + 9792, base, cbase, afft);
  __syncthreads();                                 // staging area dead -> reuse as reduce buf
  float* rs = fl;                                  // [256][25]
  float* rt = fl + 6400;                           // [256][25]
#pragma unroll
  for (int n = 0; n < 24; n++) {
    rs[(wvu * 64 + ln) * 25 + n] = affs[n];
    rt[(wvu * 64 + ln) * 25 + n] = afft[n];
  }
  __syncthreads();
  if (wvu != 0) return;
  float as_[24], at_[24];
#pragma unroll
  for (int n = 0; n < 24; n++) {
    as_[n] = rs[ln * 25 + n] + rs[(64 + ln) * 25 + n] + rs[(128 + ln) * 25 + n] + rs[(192 + ln) * 25 + n];
    at_[n] = rt[ln * 25 + n] + rt[(64 + ln) * 25 + n] + rt[(128 + ln) * 25 + n] + rt[(192 + ln) * 25 + n];
  }
  float mxt = at_[0], mxs = as_[0];
#pragma unroll
  for (int n = 1; n < 24; n++) { mxt = fmaxf(mxt, at_[n]); mxs = fmaxf(mxs, as_[n]); }
  float et[24];
  float st = 0.f, ssum = 0.f;
#pragma unroll
  for (int n = 0; n < 24; n++) {
    et[n] = expf((at_[n] - mxt) * 10.f); st += et[n];
    ssum += expf((as_[n] - mxs) * 10.f);
  }
  float lset = logf(st), lses = logf(ssum);
  float rst = 1.f / st;
  float ent = 0.f, kl = 0.f;
#pragma unroll
  for (int n = 0; n < 24; n++) {
    float tp = et[n] * rst;
    float tlp = (at_[n] - mxt) * 10.f - lset;
    float slp = (as_[n] - mxs) * 10.f - lses;
    ent -= tp * tlp;
    kl += tp * (tlp - slp);
  }
  float wconf = 1.f - ent * (1.0f / 3.17805383034794580f);   // MAXH = log(24)
  wconf = fminf(fmaxf(wconf, 0.f), 1.f);
  const int gy = ty0 + ty, gx = tx0 + tx;
  const int gpix = b * 4096 + gy * 64 + gx;
  float mnv = __uint_as_float(mnmx[b]);
  float mxv = __uint_as_float(mnmx[8 + b]);
  float wedge = (mag[gpix] - mnv) / (mxv - mnv + 1e-6f);
  float wgt = wconf * wconf * (1.f + wedge);
  if (gy < 2 || gy >= 62 || gx < 2 || gx >= 62) wgt = 0.f;
  double wkl = (double)(wgt * kl), wsum = (double)wgt;
#pragma unroll
  for (int off = 32; off >= 1; off >>= 1) {
    wkl  += __shfl_down(wkl, off);
    wsum += __shfl_down(wsum, off);
  }
  if (ln == 0) {
    atomicAdd(&accg[0], wkl);
    atomicAdd(&accg[1], wsum);
    __threadfence();
    unsigned int old = atomicAdd(cnt, 1u);
    if (old == 511u) {
      double a0 = atomicAdd(&accg[0], 0.0);
      double a1 = atomicAdd(&accg[1], 0.0);
      out[0] = (float)(a0 / (a1 + 1e-6));
    }
  }
}

extern "C" void kernel_launch(void* const* d_in, const int* in_sizes, int n_in,
                              void* d_out, int out_size, void* d_ws, size_t ws_size,
                              hipStream_t stream) {
  const float* fs3 = (const float*)d_in[0];
  const float* ft  = (const float*)d_in[1];
  const float* Ws  = (const float*)d_in[2];
  const float* Wt  = (const float*)d_in[3];
  float* out = (float*)d_out;
  float* w = (float*)d_ws;
  float* t32 = w + WS_T32;
  float* tn  = w + WS_TN;
  float* sn  = w + WS_SN;
  float* tm  = w + WS_TM;
  float* mag = w + WS_MAG;
  float* WtT = w + WS_WTT;
  float* WsT = w + WS_WST;
  unsigned int* mnmx = (unsigned int*)(w + WS_MNMX);
  double* acc = (double*)(w + WS_ACC);

  k_transw<<<192, 256, 0, stream>>>(Wt, Ws, WtT, WsT, mnmx, acc);
  k_gemm_t<<<dim3(128, 4), 512, 0, stream>>>(ft, WtT, t32);
  k_resize_norm<<<512, 256, 0, stream>>>(t32, tn, tm);
  k_sobel<<<256, 128, 0, stream>>>(tm, mag, mnmx);
  k_gemm_s<<<512, 512, 0, stream>>>(fs3, WsT, sn);
  k_aff<<<512, 256, 0, stream>>>(sn, tn, mag, mnmx, &mnmx[16], acc, out);
}